// Round 6
// baseline (1764.143 us; speedup 1.0000x reference)
//
#include <hip/hip_runtime.h>
#include <math.h>

// Problem constants
#define Hdim 768
#define NH 12
#define HD 64
#define MM 16
#define KK 4
#define Bb 4
#define Nn 2048
#define NMB 128               // Nn/MM
#define EPSV 1e-5f
#define PLD 2320              // padded width of P / Wcat (2316 cols used)
#define NCOLS 2316            // 768*3 + 12

// ---------------------------------------------------------------------------
// Static device scratch (module-load allocated; avoids any d_ws overflow).
// ---------------------------------------------------------------------------
__device__ float g_tab[1024];
__device__ float g_Wcat[(size_t)Hdim * PLD + 512];      // +guard: B-tile over-read
__device__ float g_P[(size_t)Bb * Nn * PLD + 512];
__device__ float g_XQ[(size_t)Bb * NH * Nn * HD];       // reused as ubuf after scan
__device__ float g_XK[(size_t)Bb * NH * Nn * HD];
__device__ float g_XV[(size_t)Bb * NH * Nn * HD];
__device__ float g_lrv[(size_t)Bb * NH * Nn];
__device__ float g_y[(size_t)Bb * Nn * Hdim];

// ---------------------------------------------------------------------------
// DPP-based 16-lane sum (bit-exact equivalent of shfl_xor 1,2,4,8 tree).
// ---------------------------------------------------------------------------
template <int CTRL>
__device__ __forceinline__ float dpp_mov(float x) {
    return __int_as_float(__builtin_amdgcn_update_dpp(
        0, __float_as_int(x), CTRL, 0xF, 0xF, true));
}
__device__ __forceinline__ float red16_dpp(float x) {
    x += dpp_mov<0xB1>(x);    // quad_perm [1,0,3,2]  == xor 1
    x += dpp_mov<0x4E>(x);    // quad_perm [2,3,0,1]  == xor 2
    x += dpp_mov<0x141>(x);   // row_half_mirror      == quad ^ 1 (quad-uniform by now)
    x += dpp_mov<0x140>(x);   // row_mirror           == quad-pair ^ 1
    return x;
}

// ---------------------------------------------------------------------------
// Kernel 0: pack Wcat = [wq | wv | wg | lr_w^T] and build RoPE cos/sin table
// ---------------------------------------------------------------------------
__global__ __launch_bounds__(256) void prep_kernel(
    const float* __restrict__ wq, const float* __restrict__ wv,
    const float* __restrict__ wg, const float* __restrict__ lrw,
    float* __restrict__ Wcat, float* __restrict__ tab)
{
    int idx0 = blockIdx.x * 256 + threadIdx.x;
    if (idx0 < 512) {  // 16 pos x 32 freqs
        int pos = idx0 >> 5, k = idx0 & 31;
        double f = pow(10000.0, -(double)k / 32.0);
        double a = (double)pos * f;
        tab[2 * idx0 + 0] = (float)cos(a);
        tab[2 * idx0 + 1] = (float)sin(a);
    }
    const int total = Hdim * PLD;
    for (int i = idx0; i < total; i += 2048 * 256) {
        int k = i / PLD, j = i - k * PLD;
        float v;
        if (j < 768)       v = wq[k * 768 + j];
        else if (j < 1536) v = wv[k * 768 + (j - 768)];
        else if (j < 2304) v = wg[k * 768 + (j - 1536)];
        else if (j < NCOLS) v = lrw[(j - 2304) * 768 + k];
        else v = 0.f;
        Wcat[i] = v;
    }
}

// ---------------------------------------------------------------------------
// Tiled fp32 GEMM: C[M,N] = A[M,K] * B[K,N]  (row-major, ld in elements)
// ---------------------------------------------------------------------------
__global__ __launch_bounds__(256) void gemm_tiled(
    const float* __restrict__ A, int lda,
    const float* __restrict__ Bm, int ldb,
    float* __restrict__ C, int ldc,
    int M, int N, int K)
{
    __shared__ float As[16][132];
    __shared__ float Bs[16][132];
    const int tid = threadIdx.x;
    const int tx = tid & 15, ty = tid >> 4;
    const int row0 = blockIdx.y * 128;
    const int col0 = blockIdx.x * 128;
    const int r_lo = ty * 4, c_lo = tx * 4;

    float acc[8][8];
#pragma unroll
    for (int i = 0; i < 8; ++i)
#pragma unroll
        for (int j = 0; j < 8; ++j) acc[i][j] = 0.f;

    for (int kt = 0; kt < K; kt += 16) {
#pragma unroll
        for (int i = 0; i < 2; ++i) {
            int id = tid + i * 256;
            int r = id >> 2, kq = (id & 3) * 4;
            const float4 a = *reinterpret_cast<const float4*>(
                &A[(size_t)(row0 + r) * lda + kt + kq]);
            As[kq + 0][r] = a.x; As[kq + 1][r] = a.y;
            As[kq + 2][r] = a.z; As[kq + 3][r] = a.w;
        }
#pragma unroll
        for (int i = 0; i < 2; ++i) {
            int id = tid + i * 256;
            int kr = id >> 5, jq = (id & 31) * 4;
            const float4 bv = *reinterpret_cast<const float4*>(
                &Bm[(size_t)(kt + kr) * ldb + col0 + jq]);
            *reinterpret_cast<float4*>(&Bs[kr][jq]) = bv;
        }
        __syncthreads();
#pragma unroll
        for (int k = 0; k < 16; ++k) {
            float a[8], bb[8];
            *reinterpret_cast<float4*>(&a[0]) = *reinterpret_cast<float4*>(&As[k][r_lo]);
            *reinterpret_cast<float4*>(&a[4]) = *reinterpret_cast<float4*>(&As[k][64 + r_lo]);
            *reinterpret_cast<float4*>(&bb[0]) = *reinterpret_cast<float4*>(&Bs[k][c_lo]);
            *reinterpret_cast<float4*>(&bb[4]) = *reinterpret_cast<float4*>(&Bs[k][64 + c_lo]);
#pragma unroll
            for (int i = 0; i < 8; ++i)
#pragma unroll
                for (int j = 0; j < 8; ++j)
                    acc[i][j] = fmaf(a[i], bb[j], acc[i][j]);
        }
        __syncthreads();
    }
#pragma unroll
    for (int i = 0; i < 8; ++i) {
        int rr = row0 + ((i < 4) ? (r_lo + i) : (64 + r_lo + i - 4));
        if (rr >= M) continue;
#pragma unroll
        for (int jb = 0; jb < 2; ++jb) {
            int cc = col0 + jb * 64 + c_lo;
            if (cc + 3 < N) {
                *reinterpret_cast<float4*>(&C[(size_t)rr * ldc + cc]) =
                    make_float4(acc[i][jb * 4 + 0], acc[i][jb * 4 + 1],
                                acc[i][jb * 4 + 2], acc[i][jb * 4 + 3]);
            } else {
#pragma unroll
                for (int jj = 0; jj < 4; ++jj)
                    if (cc + jj < N) C[(size_t)rr * ldc + cc + jj] = acc[i][jb * 4 + jj];
            }
        }
    }
}

// ---------------------------------------------------------------------------
// Kernel 2: causal conv + RoPE + pack + lr sigmoid.  One block per token.
// ---------------------------------------------------------------------------
__global__ __launch_bounds__(256) void conv_rope_kernel(
    const float* __restrict__ P, const int* __restrict__ pid,
    const float* __restrict__ cqk, const float* __restrict__ cqb,
    const float* __restrict__ ckk, const float* __restrict__ ckb,
    const float* __restrict__ lr_b, const float* __restrict__ tab,
    float* __restrict__ XQp, float* __restrict__ XKp, float* __restrict__ XVp,
    float* __restrict__ lrv)
{
    const int t = blockIdx.x;
    const int b = t >> 11, n = t & 2047;
    const int tid = threadIdx.x;
    __shared__ float xq_s[768], xk_s[768];
    const size_t rowP = (size_t)t * PLD;

#pragma unroll
    for (int i = 0; i < 3; ++i) {
        int c = tid + i * 256;
        float aq = cqb[c], ak = ckb[c];
#pragma unroll
        for (int w = 0; w < 4; ++w) {
            int np = n + w - 4;
            if (np >= 0) {
                float x = P[(size_t)(t + w - 4) * PLD + c];
                aq = fmaf(cqk[w * 768 + c], x, aq);
                ak = fmaf(ckk[w * 768 + c], x, ak);
            }
        }
        xq_s[c] = aq; xk_s[c] = ak;
        int h = c >> 6, d = c & 63;
        XVp[((size_t)(b * NH + h)) * (Nn * HD) + n * 64 + d] = P[rowP + 768 + c];
    }
    if (tid < NH) {
        float x = P[rowP + 2304 + tid] + lr_b[tid];
        lrv[((size_t)(b * NH + tid)) * Nn + n] = 1.f / (1.f + expf(-x));
    }
    __syncthreads();
    const int pos = pid[t] & 15;
    for (int p = tid; p < 384; p += 256) {
        int h = p >> 5, k = p & 31;
        float cv = tab[(pos * 32 + k) * 2 + 0];
        float sv = tab[(pos * 32 + k) * 2 + 1];
        int c0 = h * 64 + 2 * k;
        size_t base = ((size_t)(b * NH + h)) * (Nn * HD) + n * 64 + 2 * k;
        float x0 = xq_s[c0], x1 = xq_s[c0 + 1];
        XQp[base + 0] = x0 * cv - x1 * sv;
        XQp[base + 1] = x0 * sv + x1 * cv;
        x0 = xk_s[c0]; x1 = xk_s[c0 + 1];
        XKp[base + 0] = x0 * cv - x1 * sv;
        XKp[base + 1] = x0 * sv + x1 * cv;
    }
}

// ---------------------------------------------------------------------------
// Kernel 3: TTT scan — LDS-minimal version.
// One block per (b,h); 256 threads; 128 sequential chunks.
// W1 in registers: thread (q=tid>>6, e=tid&63) owns rows 16q..16q+15, col e.
// x tiles are NOT staged in LDS: wave-uniform slices are read via scalar/
// uniform global loads (readfirstlane-forced); per-lane slices via direct
// vector global loads (L1/L2-hot, 12KB/chunk working set).  LDS holds only
// cross-lane data: part (padded 68), grad, coef, b1 (x2), alpha, g/bt, tokv.
//   P1: part = xk@W1, xq@W1 (uniform x loads)   | barrier
//   P2: z1/zb; grad (DPP LN-bwd); coef; alpha   | barrier
//   P3: Z1_bar + out-LN + y; W1 update; b1[nxt] | barrier
// ---------------------------------------------------------------------------
__global__ __launch_bounds__(256) void ttt_scan_kernel(
    const float* __restrict__ XQp, const float* __restrict__ XKp,
    const float* __restrict__ XVp, const float* __restrict__ lrv,
    const float* __restrict__ W1g, const float* __restrict__ b1g,
    const float* __restrict__ gam, const float* __restrict__ bet,
    const float* __restrict__ tokidx, float* __restrict__ ybuf)
{
    const int h = blockIdx.x, b = blockIdx.y;
    const int bh = b * NH + h;
    const int tid = threadIdx.x;
    const int e = tid & 63, q = tid >> 6;
    const int q16 = q * 16;
    // force wave-uniform recognition for scalar-load generation
    const int q16u = __builtin_amdgcn_readfirstlane(q16);

    __shared__ float part[2][4][16][68];
    __shared__ float grad_s[16][68];
    __shared__ float b1_s[2][64], g_s[64], bt_s[64];
    __shared__ float tokv_s[16], alpha_s[16];
    __shared__ float coef_s[16][17];

    float W1own[16];
#pragma unroll
    for (int r = 0; r < 16; ++r)
        W1own[r] = W1g[h * 4096 + (q16 + r) * 64 + e];
    if (tid < 64) {
        b1_s[0][tid] = b1g[h * 64 + tid];
        g_s[tid]  = gam[h * 64 + tid];
        bt_s[tid] = bet[h * 64 + tid];
    }
    if (tid < 16)
        tokv_s[tid] = fmaxf(tokidx[tid] + 1.f / (float)(tid + 1), 0.f);

    const size_t base = (size_t)bh * (Nn * HD);
    const float* __restrict__ lrC0 = lrv + (size_t)bh * Nn;
    __syncthreads();

    float zb[4];

    for (int c = 0; c < NMB; ++c) {
        const int cur = c & 1, nxt = cur ^ 1;
        const float* __restrict__ xkC = XKp + base + (size_t)c * 1024;
        const float* __restrict__ xqC = XQp + base + (size_t)c * 1024;
        const float* __restrict__ xvC = XVp + base + (size_t)c * 1024;
        const float* __restrict__ lrC = lrC0 + c * 16;

        // ---- P1 pass A: pz = xk @ W1(rows q16..q16+15) ----
#pragma unroll
        for (int mb = 0; mb < 4; ++mb) {
            float xrow[4][16];
#pragma unroll
            for (int mm = 0; mm < 4; ++mm) {
                const float* rp = xkC + (mb * 4 + mm) * 64 + q16u;  // wave-uniform
                *reinterpret_cast<float4*>(&xrow[mm][0])  = *reinterpret_cast<const float4*>(rp + 0);
                *reinterpret_cast<float4*>(&xrow[mm][4])  = *reinterpret_cast<const float4*>(rp + 4);
                *reinterpret_cast<float4*>(&xrow[mm][8])  = *reinterpret_cast<const float4*>(rp + 8);
                *reinterpret_cast<float4*>(&xrow[mm][12]) = *reinterpret_cast<const float4*>(rp + 12);
            }
#pragma unroll
            for (int mm = 0; mm < 4; ++mm) {
                float az = 0.f;
#pragma unroll
                for (int r = 0; r < 16; ++r)
                    az = fmaf(xrow[mm][r], W1own[r], az);
                part[0][q][mb * 4 + mm][e] = az;
            }
        }
        // ---- P1 pass B: pq = xq @ W1 ----
#pragma unroll
        for (int mb = 0; mb < 4; ++mb) {
            float xrow[4][16];
#pragma unroll
            for (int mm = 0; mm < 4; ++mm) {
                const float* rp = xqC + (mb * 4 + mm) * 64 + q16u;
                *reinterpret_cast<float4*>(&xrow[mm][0])  = *reinterpret_cast<const float4*>(rp + 0);
                *reinterpret_cast<float4*>(&xrow[mm][4])  = *reinterpret_cast<const float4*>(rp + 4);
                *reinterpret_cast<float4*>(&xrow[mm][8])  = *reinterpret_cast<const float4*>(rp + 8);
                *reinterpret_cast<float4*>(&xrow[mm][12]) = *reinterpret_cast<const float4*>(rp + 12);
            }
#pragma unroll
            for (int mm = 0; mm < 4; ++mm) {
                float aq = 0.f;
#pragma unroll
                for (int r = 0; r < 16; ++r)
                    aq = fmaf(xrow[mm][r], W1own[r], aq);
                part[1][q][mb * 4 + mm][e] = aq;
            }
        }
        __syncthreads();

        // ---- P2: z1/zb reduce; LN-L2 bwd -> grad; coef; alpha ----
        {
            const int m = tid >> 4, e0 = (tid & 15) * 4;
            float4 p0 = *reinterpret_cast<float4*>(&part[0][0][m][e0]);
            float4 p1 = *reinterpret_cast<float4*>(&part[0][1][m][e0]);
            float4 p2 = *reinterpret_cast<float4*>(&part[0][2][m][e0]);
            float4 p3 = *reinterpret_cast<float4*>(&part[0][3][m][e0]);
            float4 q0 = *reinterpret_cast<float4*>(&part[1][0][m][e0]);
            float4 q1 = *reinterpret_cast<float4*>(&part[1][1][m][e0]);
            float4 q2 = *reinterpret_cast<float4*>(&part[1][2][m][e0]);
            float4 q3 = *reinterpret_cast<float4*>(&part[1][3][m][e0]);
            float z1[4];
            z1[0] = b1_s[cur][e0 + 0] + p0.x + p1.x + p2.x + p3.x;
            z1[1] = b1_s[cur][e0 + 1] + p0.y + p1.y + p2.y + p3.y;
            z1[2] = b1_s[cur][e0 + 2] + p0.z + p1.z + p2.z + p3.z;
            z1[3] = b1_s[cur][e0 + 3] + p0.w + p1.w + p2.w + p3.w;
            zb[0] = q0.x + q1.x + q2.x + q3.x;
            zb[1] = q0.y + q1.y + q2.y + q3.y;
            zb[2] = q0.z + q1.z + q2.z + q3.z;
            zb[3] = q0.w + q1.w + q2.w + q3.w;

            float lsum = red16_dpp(z1[0] + z1[1] + z1[2] + z1[3]);
            const float mu = lsum * (1.f / 64.f);
            float lss = 0.f;
#pragma unroll
            for (int jj = 0; jj < 4; ++jj) { float d = z1[jj] - mu; lss += d * d; }
            lss = red16_dpp(lss);
            const float rstd = 1.f / sqrtf(lss * (1.f / 64.f) + EPSV);

            const float4 xvv = *reinterpret_cast<const float4*>(xvC + m * 64 + e0);
            const float4 xkk = *reinterpret_cast<const float4*>(xkC + m * 64 + e0);
            const float tgt4[4] = { xvv.x - xkk.x, xvv.y - xkk.y,
                                    xvv.z - xkk.z, xvv.w - xkk.w };
            float gy[4], xh[4], sgy = 0.f, sgx = 0.f;
#pragma unroll
            for (int jj = 0; jj < 4; ++jj) {
                int ee = e0 + jj;
                xh[jj] = (z1[jj] - mu) * rstd;
                gy[jj] = (g_s[ee] * xh[jj] + bt_s[ee] - tgt4[jj]) * g_s[ee];
                sgy += gy[jj]; sgx += gy[jj] * xh[jj];
            }
            sgy = red16_dpp(sgy); sgx = red16_dpp(sgx);
            const float sc = rstd * (1.f / 64.f);
#pragma unroll
            for (int jj = 0; jj < 4; ++jj)
                grad_s[m][e0 + jj] = (64.f * gy[jj] - sgy - xh[jj] * sgx) * sc;

            // coef: cf[i3][j3] = tok[i3]*lr[j3]/64 * (1 + xq[i3].xk[j3]) for j3<=i3
            const int i3 = m, j3 = (tid & 15);
            float cf = 0.f;
            if (j3 <= i3) {
                float s = 0.f;
#pragma unroll
                for (int dq = 0; dq < 16; ++dq) {
                    float4 a  = *reinterpret_cast<const float4*>(xqC + i3 * 64 + dq * 4);
                    float4 bq = *reinterpret_cast<const float4*>(xkC + j3 * 64 + dq * 4);
                    s += a.x * bq.x + a.y * bq.y + a.z * bq.z + a.w * bq.w;
                }
                cf = tokv_s[i3] * lrC[j3] * (1.f / 64.f) * (1.f + s);
            }
            coef_s[i3][j3] = cf;
            if (tid < 16) alpha_s[tid] = tokv_s[15] * lrC[tid] * (1.f / 64.f);
        }
        __syncthreads();

        // ---- P3: Z1_bar + out-LN + y store; W1/b1 update ----
        {
            const int m = tid >> 4, e0 = (tid & 15) * 4;
            float zf[4];
#pragma unroll
            for (int jj = 0; jj < 4; ++jj) zf[jj] = zb[jj] + b1_s[cur][e0 + jj];
            for (int j = 0; j <= m; ++j) {
                float cfv = coef_s[m][j];
                float4 g4 = *reinterpret_cast<float4*>(&grad_s[j][e0]);
                zf[0] = fmaf(-cfv, g4.x, zf[0]);
                zf[1] = fmaf(-cfv, g4.y, zf[1]);
                zf[2] = fmaf(-cfv, g4.z, zf[2]);
                zf[3] = fmaf(-cfv, g4.w, zf[3]);
            }
            float lsum = red16_dpp(zf[0] + zf[1] + zf[2] + zf[3]);
            const float mu = lsum * (1.f / 64.f);
            float lss = 0.f;
#pragma unroll
            for (int jj = 0; jj < 4; ++jj) { float d = zf[jj] - mu; lss += d * d; }
            lss = red16_dpp(lss);
            const float rstd = 1.f / sqrtf(lss * (1.f / 64.f) + EPSV);
            const float4 xqv = *reinterpret_cast<const float4*>(xqC + m * 64 + e0);
            const float xq4[4] = { xqv.x, xqv.y, xqv.z, xqv.w };
            float ov[4];
#pragma unroll
            for (int jj = 0; jj < 4; ++jj) {
                int ee = e0 + jj;
                ov[jj] = xq4[jj] + ((zf[jj] - mu) * rstd * g_s[ee] + bt_s[ee]);
            }
            size_t yoff = (size_t)(b * Nn + c * 16 + m) * 768 + h * 64 + e0;
            *reinterpret_cast<float4*>(&ybuf[yoff]) =
                make_float4(ov[0], ov[1], ov[2], ov[3]);
        }
        {
            // W1 update: W1[r][e] -= sum_m alpha[m]*grad[m][e]*xk[m][r]
#pragma unroll
            for (int mb = 0; mb < 4; ++mb) {
                float xrow[4][16];
#pragma unroll
                for (int mm = 0; mm < 4; ++mm) {
                    const float* rp = xkC + (mb * 4 + mm) * 64 + q16u;  // wave-uniform
                    *reinterpret_cast<float4*>(&xrow[mm][0])  = *reinterpret_cast<const float4*>(rp + 0);
                    *reinterpret_cast<float4*>(&xrow[mm][4])  = *reinterpret_cast<const float4*>(rp + 4);
                    *reinterpret_cast<float4*>(&xrow[mm][8])  = *reinterpret_cast<const float4*>(rp + 8);
                    *reinterpret_cast<float4*>(&xrow[mm][12]) = *reinterpret_cast<const float4*>(rp + 12);
                }
#pragma unroll
                for (int mm = 0; mm < 4; ++mm) {
                    const int m = mb * 4 + mm;
                    float f = alpha_s[m] * grad_s[m][e];
#pragma unroll
                    for (int r = 0; r < 16; ++r)
                        W1own[r] = fmaf(-f, xrow[mm][r], W1own[r]);
                }
            }
            if (q == 0) {
                float sb = 0.f;
#pragma unroll
                for (int m = 0; m < 16; ++m)
                    sb += alpha_s[m] * grad_s[m][e];
                b1_s[nxt][e] = b1_s[cur][e] - sb;
            }
        }
        __syncthreads();
    }
}

// ---------------------------------------------------------------------------
// Kernel 4a: post layernorm + gelu gate -> u.  One block per token.
// ---------------------------------------------------------------------------
__global__ __launch_bounds__(256) void post_gate_kernel(
    const float* __restrict__ ybuf, const float* __restrict__ P,
    const float* __restrict__ ps, const float* __restrict__ pb,
    float* __restrict__ u)
{
    const int t = blockIdx.x;
    const int tid = threadIdx.x;
    __shared__ float red_a[4], red_b[4];
    float v[3];
    float lsum = 0.f;
#pragma unroll
    for (int i = 0; i < 3; ++i) {
        int c = tid + i * 256;
        v[i] = ybuf[(size_t)t * 768 + c];
        lsum += v[i];
    }
#pragma unroll
    for (int m = 1; m < 64; m <<= 1) lsum += __shfl_xor(lsum, m);
    if ((tid & 63) == 0) red_a[tid >> 6] = lsum;
    __syncthreads();
    const float mu = (red_a[0] + red_a[1] + red_a[2] + red_a[3]) * (1.f / 768.f);
    float lv = 0.f;
#pragma unroll
    for (int i = 0; i < 3; ++i) { float d = v[i] - mu; lv += d * d; }
#pragma unroll
    for (int m = 1; m < 64; m <<= 1) lv += __shfl_xor(lv, m);
    if ((tid & 63) == 0) red_b[tid >> 6] = lv;
    __syncthreads();
    const float var = (red_b[0] + red_b[1] + red_b[2] + red_b[3]) * (1.f / 768.f);
    const float rstd = 1.f / sqrtf(var + EPSV);
#pragma unroll
    for (int i = 0; i < 3; ++i) {
        int c = tid + i * 256;
        float g = P[(size_t)t * PLD + 1536 + c];
        float gl = 0.5f * g * (1.f + tanhf(0.7978845608028654f * (g + 0.044715f * g * g * g)));
        u[(size_t)t * 768 + c] = gl * ((v[i] - mu) * rstd * ps[c] + pb[c]);
    }
}

// ---------------------------------------------------------------------------
// Launcher — scratch comes from static device globals, NOT d_ws.
// ---------------------------------------------------------------------------
extern "C" void kernel_launch(void* const* d_in, const int* in_sizes, int n_in,
                              void* d_out, int out_size, void* d_ws, size_t ws_size,
                              hipStream_t stream)
{
    const float* hs   = (const float*)d_in[0];
    const int*   pid  = (const int*)  d_in[1];
    const float* wq   = (const float*)d_in[2];
    const float* wv   = (const float*)d_in[3];
    const float* wo   = (const float*)d_in[4];
    const float* wg   = (const float*)d_in[5];
    const float* cqk  = (const float*)d_in[6];
    const float* cqb  = (const float*)d_in[7];
    const float* ckk  = (const float*)d_in[8];
    const float* ckb  = (const float*)d_in[9];
    const float* lrw  = (const float*)d_in[10];
    const float* lrb  = (const float*)d_in[11];
    const float* lti  = (const float*)d_in[12];
    const float* gam  = (const float*)d_in[13];
    const float* bet  = (const float*)d_in[14];
    const float* ps   = (const float*)d_in[15];
    const float* pb   = (const float*)d_in[16];
    const float* W1g  = (const float*)d_in[17];
    const float* b1g  = (const float*)d_in[18];
    float* out = (float*)d_out;
    (void)d_ws; (void)ws_size; (void)in_sizes; (void)n_in; (void)out_size;

    float *tab = nullptr, *Wcat = nullptr, *P = nullptr, *XQp = nullptr,
          *XKp = nullptr, *XVp = nullptr, *lrv = nullptr, *ybuf = nullptr;
    hipGetSymbolAddress((void**)&tab,  HIP_SYMBOL(g_tab));
    hipGetSymbolAddress((void**)&Wcat, HIP_SYMBOL(g_Wcat));
    hipGetSymbolAddress((void**)&P,    HIP_SYMBOL(g_P));
    hipGetSymbolAddress((void**)&XQp,  HIP_SYMBOL(g_XQ));
    hipGetSymbolAddress((void**)&XKp,  HIP_SYMBOL(g_XK));
    hipGetSymbolAddress((void**)&XVp,  HIP_SYMBOL(g_XV));
    hipGetSymbolAddress((void**)&lrv,  HIP_SYMBOL(g_lrv));
    hipGetSymbolAddress((void**)&ybuf, HIP_SYMBOL(g_y));
    float* ubuf = XQp;   // XQp dead after scan

    hipLaunchKernelGGL(prep_kernel, dim3(2048), dim3(256), 0, stream,
                       wq, wv, wg, lrw, Wcat, tab);
    hipLaunchKernelGGL(gemm_tiled, dim3(19, 64), dim3(256), 0, stream,
                       hs, Hdim, Wcat, PLD, P, PLD, Bb * Nn, NCOLS, Hdim);
    hipLaunchKernelGGL(conv_rope_kernel, dim3(Bb * Nn), dim3(256), 0, stream,
                       P, pid, cqk, cqb, ckk, ckb, lrb, tab, XQp, XKp, XVp, lrv);
    hipLaunchKernelGGL(ttt_scan_kernel, dim3(NH, Bb), dim3(256), 0, stream,
                       XQp, XKp, XVp, lrv, W1g, b1g, gam, bet, lti, ybuf);
    hipLaunchKernelGGL(post_gate_kernel, dim3(Bb * Nn), dim3(256), 0, stream,
                       ybuf, P, ps, pb, ubuf);
    hipLaunchKernelGGL(gemm_tiled, dim3(6, 64), dim3(256), 0, stream,
                       ubuf, Hdim, wo, Hdim, out, Hdim, Bb * Nn, Hdim, Hdim);
}

// Round 7
// 1333.845 us; speedup vs baseline: 1.3226x; 1.3226x over previous
//
#include <hip/hip_runtime.h>
#include <math.h>

// Problem constants
#define Hdim 768
#define NH 12
#define HD 64
#define MM 16
#define KK 4
#define Bb 4
#define Nn 2048
#define NMB 128               // Nn/MM
#define EPSV 1e-5f
#define PLD 2320              // padded width of P / Wcat (2316 cols used)
#define NCOLS 2316            // 768*3 + 12

// ---------------------------------------------------------------------------
// Static device scratch (module-load allocated; avoids any d_ws overflow).
// ---------------------------------------------------------------------------
__device__ float g_tab[1024];
__device__ float g_Wcat[(size_t)Hdim * PLD + 512];      // +guard: B-tile over-read
__device__ float g_P[(size_t)Bb * Nn * PLD + 512];
__device__ float g_XQ[(size_t)Bb * NH * Nn * HD];       // reused as ubuf after scan
__device__ float g_XK[(size_t)Bb * NH * Nn * HD];
__device__ float g_XV[(size_t)Bb * NH * Nn * HD];
__device__ float g_lrv[(size_t)Bb * NH * Nn];
__device__ float g_y[(size_t)Bb * Nn * Hdim];

// ---------------------------------------------------------------------------
// DPP-based 16-lane sum (bit-exact equivalent of shfl_xor 1,2,4,8 tree).
// ---------------------------------------------------------------------------
template <int CTRL>
__device__ __forceinline__ float dpp_mov(float x) {
    return __int_as_float(__builtin_amdgcn_update_dpp(
        0, __float_as_int(x), CTRL, 0xF, 0xF, true));
}
__device__ __forceinline__ float red16_dpp(float x) {
    x += dpp_mov<0xB1>(x);    // quad_perm [1,0,3,2]  == xor 1
    x += dpp_mov<0x4E>(x);    // quad_perm [2,3,0,1]  == xor 2
    x += dpp_mov<0x141>(x);   // row_half_mirror      == quad ^ 1 (quad-uniform by now)
    x += dpp_mov<0x140>(x);   // row_mirror           == quad-pair ^ 1
    return x;
}

// ---------------------------------------------------------------------------
// Kernel 0: pack Wcat = [wq | wv | wg | lr_w^T] and build RoPE cos/sin table
// ---------------------------------------------------------------------------
__global__ __launch_bounds__(256) void prep_kernel(
    const float* __restrict__ wq, const float* __restrict__ wv,
    const float* __restrict__ wg, const float* __restrict__ lrw,
    float* __restrict__ Wcat, float* __restrict__ tab)
{
    int idx0 = blockIdx.x * 256 + threadIdx.x;
    if (idx0 < 512) {  // 16 pos x 32 freqs
        int pos = idx0 >> 5, k = idx0 & 31;
        double f = pow(10000.0, -(double)k / 32.0);
        double a = (double)pos * f;
        tab[2 * idx0 + 0] = (float)cos(a);
        tab[2 * idx0 + 1] = (float)sin(a);
    }
    const int total = Hdim * PLD;
    for (int i = idx0; i < total; i += 2048 * 256) {
        int k = i / PLD, j = i - k * PLD;
        float v;
        if (j < 768)       v = wq[k * 768 + j];
        else if (j < 1536) v = wv[k * 768 + (j - 768)];
        else if (j < 2304) v = wg[k * 768 + (j - 1536)];
        else if (j < NCOLS) v = lrw[(j - 2304) * 768 + k];
        else v = 0.f;
        Wcat[i] = v;
    }
}

// ---------------------------------------------------------------------------
// Tiled fp32 GEMM: C[M,N] = A[M,K] * B[K,N]  (row-major, ld in elements)
// ---------------------------------------------------------------------------
__global__ __launch_bounds__(256) void gemm_tiled(
    const float* __restrict__ A, int lda,
    const float* __restrict__ Bm, int ldb,
    float* __restrict__ C, int ldc,
    int M, int N, int K)
{
    __shared__ float As[16][132];
    __shared__ float Bs[16][132];
    const int tid = threadIdx.x;
    const int tx = tid & 15, ty = tid >> 4;
    const int row0 = blockIdx.y * 128;
    const int col0 = blockIdx.x * 128;
    const int r_lo = ty * 4, c_lo = tx * 4;

    float acc[8][8];
#pragma unroll
    for (int i = 0; i < 8; ++i)
#pragma unroll
        for (int j = 0; j < 8; ++j) acc[i][j] = 0.f;

    for (int kt = 0; kt < K; kt += 16) {
#pragma unroll
        for (int i = 0; i < 2; ++i) {
            int id = tid + i * 256;
            int r = id >> 2, kq = (id & 3) * 4;
            const float4 a = *reinterpret_cast<const float4*>(
                &A[(size_t)(row0 + r) * lda + kt + kq]);
            As[kq + 0][r] = a.x; As[kq + 1][r] = a.y;
            As[kq + 2][r] = a.z; As[kq + 3][r] = a.w;
        }
#pragma unroll
        for (int i = 0; i < 2; ++i) {
            int id = tid + i * 256;
            int kr = id >> 5, jq = (id & 31) * 4;
            const float4 bv = *reinterpret_cast<const float4*>(
                &Bm[(size_t)(kt + kr) * ldb + col0 + jq]);
            *reinterpret_cast<float4*>(&Bs[kr][jq]) = bv;
        }
        __syncthreads();
#pragma unroll
        for (int k = 0; k < 16; ++k) {
            float a[8], bb[8];
            *reinterpret_cast<float4*>(&a[0]) = *reinterpret_cast<float4*>(&As[k][r_lo]);
            *reinterpret_cast<float4*>(&a[4]) = *reinterpret_cast<float4*>(&As[k][64 + r_lo]);
            *reinterpret_cast<float4*>(&bb[0]) = *reinterpret_cast<float4*>(&Bs[k][c_lo]);
            *reinterpret_cast<float4*>(&bb[4]) = *reinterpret_cast<float4*>(&Bs[k][64 + c_lo]);
#pragma unroll
            for (int i = 0; i < 8; ++i)
#pragma unroll
                for (int j = 0; j < 8; ++j)
                    acc[i][j] = fmaf(a[i], bb[j], acc[i][j]);
        }
        __syncthreads();
    }
#pragma unroll
    for (int i = 0; i < 8; ++i) {
        int rr = row0 + ((i < 4) ? (r_lo + i) : (64 + r_lo + i - 4));
        if (rr >= M) continue;
#pragma unroll
        for (int jb = 0; jb < 2; ++jb) {
            int cc = col0 + jb * 64 + c_lo;
            if (cc + 3 < N) {
                *reinterpret_cast<float4*>(&C[(size_t)rr * ldc + cc]) =
                    make_float4(acc[i][jb * 4 + 0], acc[i][jb * 4 + 1],
                                acc[i][jb * 4 + 2], acc[i][jb * 4 + 3]);
            } else {
#pragma unroll
                for (int jj = 0; jj < 4; ++jj)
                    if (cc + jj < N) C[(size_t)rr * ldc + cc + jj] = acc[i][jb * 4 + jj];
            }
        }
    }
}

// ---------------------------------------------------------------------------
// Kernel 2: causal conv + RoPE + pack + lr sigmoid.  One block per token.
// ---------------------------------------------------------------------------
__global__ __launch_bounds__(256) void conv_rope_kernel(
    const float* __restrict__ P, const int* __restrict__ pid,
    const float* __restrict__ cqk, const float* __restrict__ cqb,
    const float* __restrict__ ckk, const float* __restrict__ ckb,
    const float* __restrict__ lr_b, const float* __restrict__ tab,
    float* __restrict__ XQp, float* __restrict__ XKp, float* __restrict__ XVp,
    float* __restrict__ lrv)
{
    const int t = blockIdx.x;
    const int b = t >> 11, n = t & 2047;
    const int tid = threadIdx.x;
    __shared__ float xq_s[768], xk_s[768];
    const size_t rowP = (size_t)t * PLD;

#pragma unroll
    for (int i = 0; i < 3; ++i) {
        int c = tid + i * 256;
        float aq = cqb[c], ak = ckb[c];
#pragma unroll
        for (int w = 0; w < 4; ++w) {
            int np = n + w - 4;
            if (np >= 0) {
                float x = P[(size_t)(t + w - 4) * PLD + c];
                aq = fmaf(cqk[w * 768 + c], x, aq);
                ak = fmaf(ckk[w * 768 + c], x, ak);
            }
        }
        xq_s[c] = aq; xk_s[c] = ak;
        int h = c >> 6, d = c & 63;
        XVp[((size_t)(b * NH + h)) * (Nn * HD) + n * 64 + d] = P[rowP + 768 + c];
    }
    if (tid < NH) {
        float x = P[rowP + 2304 + tid] + lr_b[tid];
        lrv[((size_t)(b * NH + tid)) * Nn + n] = 1.f / (1.f + expf(-x));
    }
    __syncthreads();
    const int pos = pid[t] & 15;
    for (int p = tid; p < 384; p += 256) {
        int h = p >> 5, k = p & 31;
        float cv = tab[(pos * 32 + k) * 2 + 0];
        float sv = tab[(pos * 32 + k) * 2 + 1];
        int c0 = h * 64 + 2 * k;
        size_t base = ((size_t)(b * NH + h)) * (Nn * HD) + n * 64 + 2 * k;
        float x0 = xq_s[c0], x1 = xq_s[c0 + 1];
        XQp[base + 0] = x0 * cv - x1 * sv;
        XQp[base + 1] = x0 * sv + x1 * cv;
        x0 = xk_s[c0]; x1 = xk_s[c0 + 1];
        XKp[base + 0] = x0 * cv - x1 * sv;
        XKp[base + 1] = x0 * sv + x1 * cv;
    }
}

// ---------------------------------------------------------------------------
// Kernel 3: TTT scan — r5 pipelined structure + register-cached xk slice.
// One block per (b,h); 256 threads (1 wave/SIMD -> ~512 VGPR budget).
// W1 in registers: thread (q=tid>>6, e=tid&63) owns rows 16q..16q+15, col e.
// xkc[16][16] caches the wave's xk slice from P1 so the W1 update re-reads
// registers instead of 64 ds_read_b128 per thread.
//   P1: issue prefetch(c+1); part = xk@W1 (cache xk), xq@W1   | barrier
//   P2: z1/zb; grad (DPP LN-bwd); coef; alpha; stage(c+1)     | barrier
//   P3: Z1_bar + out-LN + y; W1 update (regs); b1[nxt]        | barrier
// ---------------------------------------------------------------------------
__global__ __launch_bounds__(256) void ttt_scan_kernel(
    const float* __restrict__ XQp, const float* __restrict__ XKp,
    const float* __restrict__ XVp, const float* __restrict__ lrv,
    const float* __restrict__ W1g, const float* __restrict__ b1g,
    const float* __restrict__ gam, const float* __restrict__ bet,
    const float* __restrict__ tokidx, float* __restrict__ ybuf)
{
    const int h = blockIdx.x, b = blockIdx.y;
    const int bh = b * NH + h;
    const int tid = threadIdx.x;
    const int e = tid & 63, q = tid >> 6;
    const int q16 = q * 16;

    __shared__ float xq_s[2][16][68], xk_s[2][16][68], xv_s[2][16][68];
    __shared__ float grad_s[16][68];
    __shared__ float part[2][4][16][64];
    __shared__ float b1_s[2][64], g_s[64], bt_s[64];
    __shared__ float lrs_s[2][16], tokv_s[16], alpha_s[16];
    __shared__ float coef_s[16][17];

    float W1own[16];
#pragma unroll
    for (int r = 0; r < 16; ++r)
        W1own[r] = W1g[h * 4096 + (q16 + r) * 64 + e];
    if (tid < 64) {
        b1_s[0][tid] = b1g[h * 64 + tid];
        g_s[tid]  = gam[h * 64 + tid];
        bt_s[tid] = bet[h * 64 + tid];
    }
    if (tid < 16)
        tokv_s[tid] = fmaxf(tokidx[tid] + 1.f / (float)(tid + 1), 0.f);

    const size_t base = (size_t)bh * (Nn * HD);
    const int m_st = tid >> 4, d_st = (tid & 15) * 4;

    // ---- preload chunk 0 and stage it ----
    float4 pfq, pfk, pfv;
    float pflr = 0.f;
    {
        size_t off = base + (size_t)tid * 4;
        pfq = *reinterpret_cast<const float4*>(XQp + off);
        pfk = *reinterpret_cast<const float4*>(XKp + off);
        pfv = *reinterpret_cast<const float4*>(XVp + off);
        if (tid < 16) pflr = lrv[(size_t)bh * Nn + tid];
    }
    *reinterpret_cast<float4*>(&xq_s[0][m_st][d_st]) = pfq;
    *reinterpret_cast<float4*>(&xk_s[0][m_st][d_st]) = pfk;
    *reinterpret_cast<float4*>(&xv_s[0][m_st][d_st]) = pfv;
    if (tid < 16) lrs_s[0][tid] = pflr;
    __syncthreads();

    float zb[4];
    float xkc[16][16];      // register cache of this wave's xk slice
    int cur = 0;

    for (int c = 0; c < NMB; ++c) {
        const int nxt = cur ^ 1;

        // ---- P1: issue prefetch for c+1; compute partial products ----
        {
            const int cn = (c < NMB - 1) ? (c + 1) : c;
            size_t off = base + (size_t)cn * 1024 + tid * 4;
            pfq = *reinterpret_cast<const float4*>(XQp + off);
            pfk = *reinterpret_cast<const float4*>(XKp + off);
            pfv = *reinterpret_cast<const float4*>(XVp + off);
            if (tid < 16) pflr = lrv[(size_t)bh * Nn + cn * 16 + tid];
        }
#pragma unroll
        for (int m = 0; m < 16; ++m) {
            float xqv[16];
            *reinterpret_cast<float4*>(&xkc[m][0])  = *reinterpret_cast<float4*>(&xk_s[cur][m][q16 + 0]);
            *reinterpret_cast<float4*>(&xkc[m][4])  = *reinterpret_cast<float4*>(&xk_s[cur][m][q16 + 4]);
            *reinterpret_cast<float4*>(&xkc[m][8])  = *reinterpret_cast<float4*>(&xk_s[cur][m][q16 + 8]);
            *reinterpret_cast<float4*>(&xkc[m][12]) = *reinterpret_cast<float4*>(&xk_s[cur][m][q16 + 12]);
            *reinterpret_cast<float4*>(&xqv[0])  = *reinterpret_cast<float4*>(&xq_s[cur][m][q16 + 0]);
            *reinterpret_cast<float4*>(&xqv[4])  = *reinterpret_cast<float4*>(&xq_s[cur][m][q16 + 4]);
            *reinterpret_cast<float4*>(&xqv[8])  = *reinterpret_cast<float4*>(&xq_s[cur][m][q16 + 8]);
            *reinterpret_cast<float4*>(&xqv[12]) = *reinterpret_cast<float4*>(&xq_s[cur][m][q16 + 12]);
            float az = 0.f, aq = 0.f;
#pragma unroll
            for (int r = 0; r < 16; ++r) {
                az = fmaf(xkc[m][r], W1own[r], az);
                aq = fmaf(xqv[r], W1own[r], aq);
            }
            part[0][q][m][e] = az;
            part[1][q][m][e] = aq;
        }
        __syncthreads();

        // ---- P2: grad + coef + alpha + stage(c+1) ----
        {
            *reinterpret_cast<float4*>(&xq_s[nxt][m_st][d_st]) = pfq;
            *reinterpret_cast<float4*>(&xk_s[nxt][m_st][d_st]) = pfk;
            *reinterpret_cast<float4*>(&xv_s[nxt][m_st][d_st]) = pfv;
            if (tid < 16) lrs_s[nxt][tid] = pflr;

            const int m = tid >> 4, e0 = (tid & 15) * 4;
            float4 p0 = *reinterpret_cast<float4*>(&part[0][0][m][e0]);
            float4 p1 = *reinterpret_cast<float4*>(&part[0][1][m][e0]);
            float4 p2 = *reinterpret_cast<float4*>(&part[0][2][m][e0]);
            float4 p3 = *reinterpret_cast<float4*>(&part[0][3][m][e0]);
            float4 q0 = *reinterpret_cast<float4*>(&part[1][0][m][e0]);
            float4 q1 = *reinterpret_cast<float4*>(&part[1][1][m][e0]);
            float4 q2 = *reinterpret_cast<float4*>(&part[1][2][m][e0]);
            float4 q3 = *reinterpret_cast<float4*>(&part[1][3][m][e0]);
            float z1[4];
            z1[0] = b1_s[cur][e0 + 0] + p0.x + p1.x + p2.x + p3.x;
            z1[1] = b1_s[cur][e0 + 1] + p0.y + p1.y + p2.y + p3.y;
            z1[2] = b1_s[cur][e0 + 2] + p0.z + p1.z + p2.z + p3.z;
            z1[3] = b1_s[cur][e0 + 3] + p0.w + p1.w + p2.w + p3.w;
            zb[0] = q0.x + q1.x + q2.x + q3.x;
            zb[1] = q0.y + q1.y + q2.y + q3.y;
            zb[2] = q0.z + q1.z + q2.z + q3.z;
            zb[3] = q0.w + q1.w + q2.w + q3.w;

            float lsum = red16_dpp(z1[0] + z1[1] + z1[2] + z1[3]);
            const float mu = lsum * (1.f / 64.f);
            float lss = 0.f;
#pragma unroll
            for (int jj = 0; jj < 4; ++jj) { float d = z1[jj] - mu; lss += d * d; }
            lss = red16_dpp(lss);
            const float rstd = 1.f / sqrtf(lss * (1.f / 64.f) + EPSV);
            float gy[4], xh[4], sgy = 0.f, sgx = 0.f;
#pragma unroll
            for (int jj = 0; jj < 4; ++jj) {
                int ee = e0 + jj;
                xh[jj] = (z1[jj] - mu) * rstd;
                float tgt = xv_s[cur][m][ee] - xk_s[cur][m][ee];
                gy[jj] = (g_s[ee] * xh[jj] + bt_s[ee] - tgt) * g_s[ee];
                sgy += gy[jj]; sgx += gy[jj] * xh[jj];
            }
            sgy = red16_dpp(sgy); sgx = red16_dpp(sgx);
            const float sc = rstd * (1.f / 64.f);
#pragma unroll
            for (int jj = 0; jj < 4; ++jj)
                grad_s[m][e0 + jj] = (64.f * gy[jj] - sgy - xh[jj] * sgx) * sc;

            const int i3 = m, j3 = (tid & 15);
            float cf = 0.f;
            if (j3 <= i3) {
                float s = 0.f;
#pragma unroll
                for (int d = 0; d < 64; d += 4) {
                    float4 a  = *reinterpret_cast<float4*>(&xq_s[cur][i3][d]);
                    float4 bq = *reinterpret_cast<float4*>(&xk_s[cur][j3][d]);
                    s += a.x * bq.x + a.y * bq.y + a.z * bq.z + a.w * bq.w;
                }
                cf = tokv_s[i3] * lrs_s[cur][j3] * (1.f / 64.f) * (1.f + s);
            }
            coef_s[i3][j3] = cf;
            if (tid < 16) alpha_s[tid] = tokv_s[15] * lrs_s[cur][tid] * (1.f / 64.f);
        }
        __syncthreads();

        // ---- P3: Z1_bar + out-LN + y; W1/b1 update (xk from registers) ----
        {
            const int m = tid >> 4, e0 = (tid & 15) * 4;
            float zf[4];
#pragma unroll
            for (int jj = 0; jj < 4; ++jj) zf[jj] = zb[jj] + b1_s[cur][e0 + jj];
            for (int j = 0; j <= m; ++j) {
                float cfv = coef_s[m][j];
                float4 g4 = *reinterpret_cast<float4*>(&grad_s[j][e0]);
                zf[0] = fmaf(-cfv, g4.x, zf[0]);
                zf[1] = fmaf(-cfv, g4.y, zf[1]);
                zf[2] = fmaf(-cfv, g4.z, zf[2]);
                zf[3] = fmaf(-cfv, g4.w, zf[3]);
            }
            float lsum = red16_dpp(zf[0] + zf[1] + zf[2] + zf[3]);
            const float mu = lsum * (1.f / 64.f);
            float lss = 0.f;
#pragma unroll
            for (int jj = 0; jj < 4; ++jj) { float d = zf[jj] - mu; lss += d * d; }
            lss = red16_dpp(lss);
            const float rstd = 1.f / sqrtf(lss * (1.f / 64.f) + EPSV);
            float ov[4];
#pragma unroll
            for (int jj = 0; jj < 4; ++jj) {
                int ee = e0 + jj;
                ov[jj] = xq_s[cur][m][ee] + ((zf[jj] - mu) * rstd * g_s[ee] + bt_s[ee]);
            }
            size_t yoff = (size_t)(b * Nn + c * 16 + m) * 768 + h * 64 + e0;
            *reinterpret_cast<float4*>(&ybuf[yoff]) =
                make_float4(ov[0], ov[1], ov[2], ov[3]);
        }
        {
#pragma unroll
            for (int m = 0; m < 16; ++m) {
                float f = alpha_s[m] * grad_s[m][e];
#pragma unroll
                for (int r = 0; r < 16; ++r)
                    W1own[r] = fmaf(-f, xkc[m][r], W1own[r]);
            }
            if (q == 0) {
                float sb = 0.f;
#pragma unroll
                for (int m = 0; m < 16; ++m)
                    sb += alpha_s[m] * grad_s[m][e];
                b1_s[nxt][e] = b1_s[cur][e] - sb;
            }
        }
        __syncthreads();
        cur = nxt;
    }
}

// ---------------------------------------------------------------------------
// Kernel 4a: post layernorm + gelu gate -> u.  One block per token.
// ---------------------------------------------------------------------------
__global__ __launch_bounds__(256) void post_gate_kernel(
    const float* __restrict__ ybuf, const float* __restrict__ P,
    const float* __restrict__ ps, const float* __restrict__ pb,
    float* __restrict__ u)
{
    const int t = blockIdx.x;
    const int tid = threadIdx.x;
    __shared__ float red_a[4], red_b[4];
    float v[3];
    float lsum = 0.f;
#pragma unroll
    for (int i = 0; i < 3; ++i) {
        int c = tid + i * 256;
        v[i] = ybuf[(size_t)t * 768 + c];
        lsum += v[i];
    }
#pragma unroll
    for (int m = 1; m < 64; m <<= 1) lsum += __shfl_xor(lsum, m);
    if ((tid & 63) == 0) red_a[tid >> 6] = lsum;
    __syncthreads();
    const float mu = (red_a[0] + red_a[1] + red_a[2] + red_a[3]) * (1.f / 768.f);
    float lv = 0.f;
#pragma unroll
    for (int i = 0; i < 3; ++i) { float d = v[i] - mu; lv += d * d; }
#pragma unroll
    for (int m = 1; m < 64; m <<= 1) lv += __shfl_xor(lv, m);
    if ((tid & 63) == 0) red_b[tid >> 6] = lv;
    __syncthreads();
    const float var = (red_b[0] + red_b[1] + red_b[2] + red_b[3]) * (1.f / 768.f);
    const float rstd = 1.f / sqrtf(var + EPSV);
#pragma unroll
    for (int i = 0; i < 3; ++i) {
        int c = tid + i * 256;
        float g = P[(size_t)t * PLD + 1536 + c];
        float gl = 0.5f * g * (1.f + tanhf(0.7978845608028654f * (g + 0.044715f * g * g * g)));
        u[(size_t)t * 768 + c] = gl * ((v[i] - mu) * rstd * ps[c] + pb[c]);
    }
}

// ---------------------------------------------------------------------------
// Launcher — scratch comes from static device globals, NOT d_ws.
// ---------------------------------------------------------------------------
extern "C" void kernel_launch(void* const* d_in, const int* in_sizes, int n_in,
                              void* d_out, int out_size, void* d_ws, size_t ws_size,
                              hipStream_t stream)
{
    const float* hs   = (const float*)d_in[0];
    const int*   pid  = (const int*)  d_in[1];
    const float* wq   = (const float*)d_in[2];
    const float* wv   = (const float*)d_in[3];
    const float* wo   = (const float*)d_in[4];
    const float* wg   = (const float*)d_in[5];
    const float* cqk  = (const float*)d_in[6];
    const float* cqb  = (const float*)d_in[7];
    const float* ckk  = (const float*)d_in[8];
    const float* ckb  = (const float*)d_in[9];
    const float* lrw  = (const float*)d_in[10];
    const float* lrb  = (const float*)d_in[11];
    const float* lti  = (const float*)d_in[12];
    const float* gam  = (const float*)d_in[13];
    const float* bet  = (const float*)d_in[14];
    const float* ps   = (const float*)d_in[15];
    const float* pb   = (const float*)d_in[16];
    const float* W1g  = (const float*)d_in[17];
    const float* b1g  = (const float*)d_in[18];
    float* out = (float*)d_out;
    (void)d_ws; (void)ws_size; (void)in_sizes; (void)n_in; (void)out_size;

    float *tab = nullptr, *Wcat = nullptr, *P = nullptr, *XQp = nullptr,
          *XKp = nullptr, *XVp = nullptr, *lrv = nullptr, *ybuf = nullptr;
    hipGetSymbolAddress((void**)&tab,  HIP_SYMBOL(g_tab));
    hipGetSymbolAddress((void**)&Wcat, HIP_SYMBOL(g_Wcat));
    hipGetSymbolAddress((void**)&P,    HIP_SYMBOL(g_P));
    hipGetSymbolAddress((void**)&XQp,  HIP_SYMBOL(g_XQ));
    hipGetSymbolAddress((void**)&XKp,  HIP_SYMBOL(g_XK));
    hipGetSymbolAddress((void**)&XVp,  HIP_SYMBOL(g_XV));
    hipGetSymbolAddress((void**)&lrv,  HIP_SYMBOL(g_lrv));
    hipGetSymbolAddress((void**)&ybuf, HIP_SYMBOL(g_y));
    float* ubuf = XQp;   // XQp dead after scan

    hipLaunchKernelGGL(prep_kernel, dim3(2048), dim3(256), 0, stream,
                       wq, wv, wg, lrw, Wcat, tab);
    hipLaunchKernelGGL(gemm_tiled, dim3(19, 64), dim3(256), 0, stream,
                       hs, Hdim, Wcat, PLD, P, PLD, Bb * Nn, NCOLS, Hdim);
    hipLaunchKernelGGL(conv_rope_kernel, dim3(Bb * Nn), dim3(256), 0, stream,
                       P, pid, cqk, cqb, ckk, ckb, lrb, tab, XQp, XKp, XVp, lrv);
    hipLaunchKernelGGL(ttt_scan_kernel, dim3(NH, Bb), dim3(256), 0, stream,
                       XQp, XKp, XVp, lrv, W1g, b1g, gam, bet, lti, ybuf);
    hipLaunchKernelGGL(post_gate_kernel, dim3(Bb * Nn), dim3(256), 0, stream,
                       ybuf, P, ps, pb, ubuf);
    hipLaunchKernelGGL(gemm_tiled, dim3(6, 64), dim3(256), 0, stream,
                       ubuf, Hdim, wo, Hdim, out, Hdim, Bb * Nn, Hdim, Hdim);
}

// Round 8
// 1098.039 us; speedup vs baseline: 1.6066x; 1.2148x over previous
//
#include <hip/hip_runtime.h>
#include <math.h>

// Problem constants
#define Hdim 768
#define NH 12
#define HD 64
#define MM 16
#define KK 4
#define Bb 4
#define Nn 2048
#define NMB 128               // Nn/MM
#define EPSV 1e-5f
#define PLD 2320              // padded width of P / Wcat (2316 cols used)
#define NCOLS 2316            // 768*3 + 12

typedef __attribute__((ext_vector_type(8))) short short8;
typedef __attribute__((ext_vector_type(4))) float f32x4;

// ---------------------------------------------------------------------------
// Static device scratch (module-load allocated; avoids any d_ws overflow).
// ---------------------------------------------------------------------------
__device__ float g_tab[1024];
__device__ float g_Wcat[(size_t)Hdim * PLD + 512];      // +guard: B over-read
__device__ float g_P[(size_t)Bb * Nn * PLD + 512];
__device__ float g_XQ[(size_t)Bb * NH * Nn * HD];       // reused as ubuf after scan
__device__ float g_XK[(size_t)Bb * NH * Nn * HD];
__device__ float g_XV[(size_t)Bb * NH * Nn * HD];
__device__ float g_lrv[(size_t)Bb * NH * Nn];
__device__ float g_y[(size_t)Bb * Nn * Hdim];
__device__ int   g_mfma_ok;                              // set by mfma_probe

// ---------------------------------------------------------------------------
// DPP-based 16-lane sum (bit-exact equivalent of shfl_xor 1,2,4,8 tree).
// ---------------------------------------------------------------------------
template <int CTRL>
__device__ __forceinline__ float dpp_mov(float x) {
    return __int_as_float(__builtin_amdgcn_update_dpp(
        0, __float_as_int(x), CTRL, 0xF, 0xF, true));
}
__device__ __forceinline__ float red16_dpp(float x) {
    x += dpp_mov<0xB1>(x);
    x += dpp_mov<0x4E>(x);
    x += dpp_mov<0x141>(x);
    x += dpp_mov<0x140>(x);
    return x;
}

// RNE fp32 -> 2x bf16 split: hi = bf16(a), lo = bf16(a - hi)
__device__ __forceinline__ void cvt2(float a, float b, unsigned &hi, unsigned &lo) {
    unsigned ua = __float_as_uint(a); unsigned ra = (ua + 0x7FFFu + ((ua >> 16) & 1u)) >> 16;
    unsigned ub = __float_as_uint(b); unsigned rb = (ub + 0x7FFFu + ((ub >> 16) & 1u)) >> 16;
    hi = ra | (rb << 16);
    float la = a - __uint_as_float(ra << 16);
    float lb = b - __uint_as_float(rb << 16);
    unsigned ula = __float_as_uint(la); ula = (ula + 0x7FFFu + ((ula >> 16) & 1u)) >> 16;
    unsigned ulb = __float_as_uint(lb); ulb = (ulb + 0x7FFFu + ((ulb >> 16) & 1u)) >> 16;
    lo = ula | (ulb << 16);
}

// ---------------------------------------------------------------------------
// MFMA layout probe: validates (A-pack, B-pack, D-read) composition for
// v_mfma_f32_16x16x32_bf16 with asymmetric integer matrices (bf16-exact).
// Assumed: A[row=l&15][k=(l>>4)*8+j]; B[k=(l>>4)*8+j][col=l&15];
//          D[row=(l>>4)*4+i][col=l&15].
// ---------------------------------------------------------------------------
__global__ void mfma_probe() {
    const int l = threadIdx.x;
    short8 af, bf;
#pragma unroll
    for (int j = 0; j < 8; ++j) {
        int k = (l >> 4) * 8 + j;
        int r = l & 15;
        float aval = (float)(((r * 5 + k * 3) % 7) - 3);
        float bval = (float)(((k * 11 + (l & 15) * 2) % 5) - 2);
        af[j] = (short)(__float_as_uint(aval) >> 16);
        bf[j] = (short)(__float_as_uint(bval) >> 16);
    }
    f32x4 z = {0.f, 0.f, 0.f, 0.f};
    f32x4 d = __builtin_amdgcn_mfma_f32_16x16x32_bf16(af, bf, z, 0, 0, 0);
    bool ok = true;
#pragma unroll
    for (int i = 0; i < 4; ++i) {
        int row = (l >> 4) * 4 + i, col = l & 15;
        int ref = 0;
        for (int k = 0; k < 32; ++k)
            ref += (((row * 5 + k * 3) % 7) - 3) * (((k * 11 + col * 2) % 5) - 2);
        ok = ok && (fabsf(d[i] - (float)ref) < 0.5f);
    }
    unsigned long long m = __ballot(ok);
    if (l == 0) g_mfma_ok = (m == 0xFFFFFFFFFFFFFFFFULL) ? 1 : 0;
}

// ---------------------------------------------------------------------------
// Kernel 0: pack Wcat = [wq | wv | wg | lr_w^T] and build RoPE cos/sin table
// ---------------------------------------------------------------------------
__global__ __launch_bounds__(256) void prep_kernel(
    const float* __restrict__ wq, const float* __restrict__ wv,
    const float* __restrict__ wg, const float* __restrict__ lrw,
    float* __restrict__ Wcat, float* __restrict__ tab)
{
    int idx0 = blockIdx.x * 256 + threadIdx.x;
    if (idx0 < 512) {
        int pos = idx0 >> 5, k = idx0 & 31;
        double f = pow(10000.0, -(double)k / 32.0);
        double a = (double)pos * f;
        tab[2 * idx0 + 0] = (float)cos(a);
        tab[2 * idx0 + 1] = (float)sin(a);
    }
    const int total = Hdim * PLD;
    for (int i = idx0; i < total; i += 2048 * 256) {
        int k = i / PLD, j = i - k * PLD;
        float v;
        if (j < 768)       v = wq[k * 768 + j];
        else if (j < 1536) v = wv[k * 768 + (j - 768)];
        else if (j < 2304) v = wg[k * 768 + (j - 1536)];
        else if (j < NCOLS) v = lrw[(j - 2304) * 768 + k];
        else v = 0.f;
        Wcat[i] = v;
    }
}

// ---------------------------------------------------------------------------
// GEMM: C[M,N] = A[M,K]*B[K,N], fp32 in/out.
// If g_mfma_ok: split-bf16 MFMA path (128x128 tile, 4 waves, 16x16x32 bf16,
// acc += Ah*Bh + Ah*Bl + Al*Bh).  Else: fp32 fallback (r5 gemm_tiled body).
// LDS (40KB): Ah/Al [128][40] ushort, Bh/Bl [128 cols][40 k] ushort (aliased
// by fp32 path as As[16][132]+Bs[16][132] floats).
// ---------------------------------------------------------------------------
__global__ __launch_bounds__(256) void gemm_bf16x3(
    const float* __restrict__ A, int lda,
    const float* __restrict__ Bm, int ldb,
    float* __restrict__ C, int ldc,
    int M, int N, int K)
{
    __shared__ unsigned smem[10240];   // 40 KB
    const int tid = threadIdx.x;
    const int row0 = blockIdx.y * 128;
    const int col0 = blockIdx.x * 128;

    if (g_mfma_ok) {
        unsigned* Ah = smem;               // [128][20] uints (40 bf16/row)
        unsigned* Al = smem + 2560;
        unsigned* Bh = smem + 5120;        // [col][k] same stride
        unsigned* Bl = smem + 7680;
        const int lane = tid & 63, wv = tid >> 6;
        const int wr = wv >> 1, wc = wv & 1;
        const int l15 = lane & 15, lg = lane >> 4;

        f32x4 acc[4][4];
#pragma unroll
        for (int i = 0; i < 4; ++i)
#pragma unroll
            for (int j = 0; j < 4; ++j) acc[i][j] = f32x4{0.f, 0.f, 0.f, 0.f};

        const int bcol = tid & 127, bkh = tid >> 7;

        for (int kt = 0; kt < K; kt += 32) {
            if (kt) __syncthreads();
            // stage A (128 rows x 32 k)
#pragma unroll
            for (int it = 0; it < 4; ++it) {
                int id = tid + it * 256;
                int r = id >> 3, kq = (id & 7) * 4;
                const float4 av = *reinterpret_cast<const float4*>(
                    &A[(size_t)(row0 + r) * lda + kt + kq]);
                unsigned h0, l0, h1, l1;
                cvt2(av.x, av.y, h0, l0);
                cvt2(av.z, av.w, h1, l1);
                int idx = r * 20 + (kq >> 1);
                Ah[idx] = h0; Ah[idx + 1] = h1;
                Al[idx] = l0; Al[idx + 1] = l1;
            }
            // stage B transposed: Bt[col][k]
            {
                float bv[16];
#pragma unroll
                for (int j = 0; j < 16; ++j)
                    bv[j] = Bm[(size_t)(kt + bkh * 16 + j) * ldb + col0 + bcol];
                unsigned hb[8], lb[8];
#pragma unroll
                for (int t = 0; t < 8; ++t)
                    cvt2(bv[2 * t], bv[2 * t + 1], hb[t], lb[t]);
                int base = bcol * 20 + bkh * 8;
                *reinterpret_cast<uint4*>(&Bh[base])     = *reinterpret_cast<uint4*>(&hb[0]);
                *reinterpret_cast<uint4*>(&Bh[base + 4]) = *reinterpret_cast<uint4*>(&hb[4]);
                *reinterpret_cast<uint4*>(&Bl[base])     = *reinterpret_cast<uint4*>(&lb[0]);
                *reinterpret_cast<uint4*>(&Bl[base + 4]) = *reinterpret_cast<uint4*>(&lb[4]);
            }
            __syncthreads();
            short8 ahf[4], alf[4], bhf[4], blf[4];
#pragma unroll
            for (int fr = 0; fr < 4; ++fr) {
                int idx = (wr * 64 + fr * 16 + l15) * 20 + lg * 4;
                ahf[fr] = *reinterpret_cast<short8*>(&Ah[idx]);
                alf[fr] = *reinterpret_cast<short8*>(&Al[idx]);
            }
#pragma unroll
            for (int fc = 0; fc < 4; ++fc) {
                int idx = (wc * 64 + fc * 16 + l15) * 20 + lg * 4;
                bhf[fc] = *reinterpret_cast<short8*>(&Bh[idx]);
                blf[fc] = *reinterpret_cast<short8*>(&Bl[idx]);
            }
#pragma unroll
            for (int fr = 0; fr < 4; ++fr)
#pragma unroll
                for (int fc = 0; fc < 4; ++fc) {
                    acc[fr][fc] = __builtin_amdgcn_mfma_f32_16x16x32_bf16(
                        ahf[fr], bhf[fc], acc[fr][fc], 0, 0, 0);
                    acc[fr][fc] = __builtin_amdgcn_mfma_f32_16x16x32_bf16(
                        ahf[fr], blf[fc], acc[fr][fc], 0, 0, 0);
                    acc[fr][fc] = __builtin_amdgcn_mfma_f32_16x16x32_bf16(
                        alf[fr], bhf[fc], acc[fr][fc], 0, 0, 0);
                }
        }
        // epilogue: D[row=(l>>4)*4+i][col=l&15]
#pragma unroll
        for (int fr = 0; fr < 4; ++fr)
#pragma unroll
            for (int fc = 0; fc < 4; ++fc) {
                int col = col0 + wc * 64 + fc * 16 + l15;
                if (col >= N) continue;
                int rbase = row0 + wr * 64 + fr * 16 + lg * 4;
#pragma unroll
                for (int i = 0; i < 4; ++i)
                    C[(size_t)(rbase + i) * ldc + col] = acc[fr][fc][i];
            }
        return;
    }

    // -------------------- fp32 fallback path --------------------
    float* As = reinterpret_cast<float*>(smem);          // [16][132]
    float* Bs = As + 16 * 132;                           // [16][132]
    const int tx = tid & 15, ty = tid >> 4;
    const int r_lo = ty * 4, c_lo = tx * 4;

    float acc[8][8];
#pragma unroll
    for (int i = 0; i < 8; ++i)
#pragma unroll
        for (int j = 0; j < 8; ++j) acc[i][j] = 0.f;

    for (int kt = 0; kt < K; kt += 16) {
#pragma unroll
        for (int i = 0; i < 2; ++i) {
            int id = tid + i * 256;
            int r = id >> 2, kq = (id & 3) * 4;
            const float4 a = *reinterpret_cast<const float4*>(
                &A[(size_t)(row0 + r) * lda + kt + kq]);
            As[(kq + 0) * 132 + r] = a.x; As[(kq + 1) * 132 + r] = a.y;
            As[(kq + 2) * 132 + r] = a.z; As[(kq + 3) * 132 + r] = a.w;
        }
#pragma unroll
        for (int i = 0; i < 2; ++i) {
            int id = tid + i * 256;
            int kr = id >> 5, jq = (id & 31) * 4;
            const float4 bv = *reinterpret_cast<const float4*>(
                &Bm[(size_t)(kt + kr) * ldb + col0 + jq]);
            *reinterpret_cast<float4*>(&Bs[kr * 132 + jq]) = bv;
        }
        __syncthreads();
#pragma unroll
        for (int k = 0; k < 16; ++k) {
            float a[8], bb[8];
            *reinterpret_cast<float4*>(&a[0]) = *reinterpret_cast<float4*>(&As[k * 132 + r_lo]);
            *reinterpret_cast<float4*>(&a[4]) = *reinterpret_cast<float4*>(&As[k * 132 + 64 + r_lo]);
            *reinterpret_cast<float4*>(&bb[0]) = *reinterpret_cast<float4*>(&Bs[k * 132 + c_lo]);
            *reinterpret_cast<float4*>(&bb[4]) = *reinterpret_cast<float4*>(&Bs[k * 132 + 64 + c_lo]);
#pragma unroll
            for (int i = 0; i < 8; ++i)
#pragma unroll
                for (int j = 0; j < 8; ++j)
                    acc[i][j] = fmaf(a[i], bb[j], acc[i][j]);
        }
        __syncthreads();
    }
#pragma unroll
    for (int i = 0; i < 8; ++i) {
        int rr = row0 + ((i < 4) ? (r_lo + i) : (64 + r_lo + i - 4));
        if (rr >= M) continue;
#pragma unroll
        for (int jb = 0; jb < 2; ++jb) {
            int cc = col0 + jb * 64 + c_lo;
            if (cc + 3 < N) {
                *reinterpret_cast<float4*>(&C[(size_t)rr * ldc + cc]) =
                    make_float4(acc[i][jb * 4 + 0], acc[i][jb * 4 + 1],
                                acc[i][jb * 4 + 2], acc[i][jb * 4 + 3]);
            } else {
#pragma unroll
                for (int jj = 0; jj < 4; ++jj)
                    if (cc + jj < N) C[(size_t)rr * ldc + cc + jj] = acc[i][jb * 4 + jj];
            }
        }
    }
}

// ---------------------------------------------------------------------------
// Kernel 2: causal conv + RoPE + pack + lr sigmoid.  One block per token.
// ---------------------------------------------------------------------------
__global__ __launch_bounds__(256) void conv_rope_kernel(
    const float* __restrict__ P, const int* __restrict__ pid,
    const float* __restrict__ cqk, const float* __restrict__ cqb,
    const float* __restrict__ ckk, const float* __restrict__ ckb,
    const float* __restrict__ lr_b, const float* __restrict__ tab,
    float* __restrict__ XQp, float* __restrict__ XKp, float* __restrict__ XVp,
    float* __restrict__ lrv)
{
    const int t = blockIdx.x;
    const int b = t >> 11, n = t & 2047;
    const int tid = threadIdx.x;
    __shared__ float xq_s[768], xk_s[768];
    const size_t rowP = (size_t)t * PLD;

#pragma unroll
    for (int i = 0; i < 3; ++i) {
        int c = tid + i * 256;
        float aq = cqb[c], ak = ckb[c];
#pragma unroll
        for (int w = 0; w < 4; ++w) {
            int np = n + w - 4;
            if (np >= 0) {
                float x = P[(size_t)(t + w - 4) * PLD + c];
                aq = fmaf(cqk[w * 768 + c], x, aq);
                ak = fmaf(ckk[w * 768 + c], x, ak);
            }
        }
        xq_s[c] = aq; xk_s[c] = ak;
        int h = c >> 6, d = c & 63;
        XVp[((size_t)(b * NH + h)) * (Nn * HD) + n * 64 + d] = P[rowP + 768 + c];
    }
    if (tid < NH) {
        float x = P[rowP + 2304 + tid] + lr_b[tid];
        lrv[((size_t)(b * NH + tid)) * Nn + n] = 1.f / (1.f + expf(-x));
    }
    __syncthreads();
    const int pos = pid[t] & 15;
    for (int p = tid; p < 384; p += 256) {
        int h = p >> 5, k = p & 31;
        float cv = tab[(pos * 32 + k) * 2 + 0];
        float sv = tab[(pos * 32 + k) * 2 + 1];
        int c0 = h * 64 + 2 * k;
        size_t base = ((size_t)(b * NH + h)) * (Nn * HD) + n * 64 + 2 * k;
        float x0 = xq_s[c0], x1 = xq_s[c0 + 1];
        XQp[base + 0] = x0 * cv - x1 * sv;
        XQp[base + 1] = x0 * sv + x1 * cv;
        x0 = xk_s[c0]; x1 = xk_s[c0 + 1];
        XKp[base + 0] = x0 * cv - x1 * sv;
        XKp[base + 1] = x0 * sv + x1 * cv;
    }
}

// ---------------------------------------------------------------------------
// Kernel 3: TTT scan — r5 pipelined 3-barrier version (known-best, 613 us).
// ---------------------------------------------------------------------------
__global__ __launch_bounds__(256) void ttt_scan_kernel(
    const float* __restrict__ XQp, const float* __restrict__ XKp,
    const float* __restrict__ XVp, const float* __restrict__ lrv,
    const float* __restrict__ W1g, const float* __restrict__ b1g,
    const float* __restrict__ gam, const float* __restrict__ bet,
    const float* __restrict__ tokidx, float* __restrict__ ybuf)
{
    const int h = blockIdx.x, b = blockIdx.y;
    const int bh = b * NH + h;
    const int tid = threadIdx.x;
    const int e = tid & 63, q = tid >> 6;
    const int q16 = q * 16;

    __shared__ float xq_s[2][16][68], xk_s[2][16][68], xv_s[2][16][68];
    __shared__ float grad_s[16][68];
    __shared__ float part[2][4][16][64];
    __shared__ float b1_s[2][64], g_s[64], bt_s[64];
    __shared__ float lrs_s[2][16], tokv_s[16], alpha_s[16];
    __shared__ float coef_s[16][17];

    float W1own[16];
#pragma unroll
    for (int r = 0; r < 16; ++r)
        W1own[r] = W1g[h * 4096 + (q16 + r) * 64 + e];
    if (tid < 64) {
        b1_s[0][tid] = b1g[h * 64 + tid];
        g_s[tid]  = gam[h * 64 + tid];
        bt_s[tid] = bet[h * 64 + tid];
    }
    if (tid < 16)
        tokv_s[tid] = fmaxf(tokidx[tid] + 1.f / (float)(tid + 1), 0.f);

    const size_t base = (size_t)bh * (Nn * HD);
    const int m_st = tid >> 4, d_st = (tid & 15) * 4;

    float4 pfq, pfk, pfv;
    float pflr = 0.f;
    {
        size_t off = base + (size_t)tid * 4;
        pfq = *reinterpret_cast<const float4*>(XQp + off);
        pfk = *reinterpret_cast<const float4*>(XKp + off);
        pfv = *reinterpret_cast<const float4*>(XVp + off);
        if (tid < 16) pflr = lrv[(size_t)bh * Nn + tid];
    }
    *reinterpret_cast<float4*>(&xq_s[0][m_st][d_st]) = pfq;
    *reinterpret_cast<float4*>(&xk_s[0][m_st][d_st]) = pfk;
    *reinterpret_cast<float4*>(&xv_s[0][m_st][d_st]) = pfv;
    if (tid < 16) lrs_s[0][tid] = pflr;
    __syncthreads();

    float zb[4];
    int cur = 0;

    for (int c = 0; c < NMB; ++c) {
        const int nxt = cur ^ 1;

        {
            const int cn = (c < NMB - 1) ? (c + 1) : c;
            size_t off = base + (size_t)cn * 1024 + tid * 4;
            pfq = *reinterpret_cast<const float4*>(XQp + off);
            pfk = *reinterpret_cast<const float4*>(XKp + off);
            pfv = *reinterpret_cast<const float4*>(XVp + off);
            if (tid < 16) pflr = lrv[(size_t)bh * Nn + cn * 16 + tid];
        }
#pragma unroll
        for (int m = 0; m < 16; ++m) {
            float xkv[16], xqv[16];
            *reinterpret_cast<float4*>(&xkv[0])  = *reinterpret_cast<float4*>(&xk_s[cur][m][q16 + 0]);
            *reinterpret_cast<float4*>(&xkv[4])  = *reinterpret_cast<float4*>(&xk_s[cur][m][q16 + 4]);
            *reinterpret_cast<float4*>(&xkv[8])  = *reinterpret_cast<float4*>(&xk_s[cur][m][q16 + 8]);
            *reinterpret_cast<float4*>(&xkv[12]) = *reinterpret_cast<float4*>(&xk_s[cur][m][q16 + 12]);
            *reinterpret_cast<float4*>(&xqv[0])  = *reinterpret_cast<float4*>(&xq_s[cur][m][q16 + 0]);
            *reinterpret_cast<float4*>(&xqv[4])  = *reinterpret_cast<float4*>(&xq_s[cur][m][q16 + 4]);
            *reinterpret_cast<float4*>(&xqv[8])  = *reinterpret_cast<float4*>(&xq_s[cur][m][q16 + 8]);
            *reinterpret_cast<float4*>(&xqv[12]) = *reinterpret_cast<float4*>(&xq_s[cur][m][q16 + 12]);
            float az = 0.f, aq = 0.f;
#pragma unroll
            for (int r = 0; r < 16; ++r) {
                az = fmaf(xkv[r], W1own[r], az);
                aq = fmaf(xqv[r], W1own[r], aq);
            }
            part[0][q][m][e] = az;
            part[1][q][m][e] = aq;
        }
        __syncthreads();

        {
            *reinterpret_cast<float4*>(&xq_s[nxt][m_st][d_st]) = pfq;
            *reinterpret_cast<float4*>(&xk_s[nxt][m_st][d_st]) = pfk;
            *reinterpret_cast<float4*>(&xv_s[nxt][m_st][d_st]) = pfv;
            if (tid < 16) lrs_s[nxt][tid] = pflr;

            const int m = tid >> 4, e0 = (tid & 15) * 4;
            float4 p0 = *reinterpret_cast<float4*>(&part[0][0][m][e0]);
            float4 p1 = *reinterpret_cast<float4*>(&part[0][1][m][e0]);
            float4 p2 = *reinterpret_cast<float4*>(&part[0][2][m][e0]);
            float4 p3 = *reinterpret_cast<float4*>(&part[0][3][m][e0]);
            float4 q0 = *reinterpret_cast<float4*>(&part[1][0][m][e0]);
            float4 q1 = *reinterpret_cast<float4*>(&part[1][1][m][e0]);
            float4 q2 = *reinterpret_cast<float4*>(&part[1][2][m][e0]);
            float4 q3 = *reinterpret_cast<float4*>(&part[1][3][m][e0]);
            float z1[4];
            z1[0] = b1_s[cur][e0 + 0] + p0.x + p1.x + p2.x + p3.x;
            z1[1] = b1_s[cur][e0 + 1] + p0.y + p1.y + p2.y + p3.y;
            z1[2] = b1_s[cur][e0 + 2] + p0.z + p1.z + p2.z + p3.z;
            z1[3] = b1_s[cur][e0 + 3] + p0.w + p1.w + p2.w + p3.w;
            zb[0] = q0.x + q1.x + q2.x + q3.x;
            zb[1] = q0.y + q1.y + q2.y + q3.y;
            zb[2] = q0.z + q1.z + q2.z + q3.z;
            zb[3] = q0.w + q1.w + q2.w + q3.w;

            float lsum = red16_dpp(z1[0] + z1[1] + z1[2] + z1[3]);
            const float mu = lsum * (1.f / 64.f);
            float lss = 0.f;
#pragma unroll
            for (int jj = 0; jj < 4; ++jj) { float d = z1[jj] - mu; lss += d * d; }
            lss = red16_dpp(lss);
            const float rstd = 1.f / sqrtf(lss * (1.f / 64.f) + EPSV);
            float gy[4], xh[4], sgy = 0.f, sgx = 0.f;
#pragma unroll
            for (int jj = 0; jj < 4; ++jj) {
                int ee = e0 + jj;
                xh[jj] = (z1[jj] - mu) * rstd;
                float tgt = xv_s[cur][m][ee] - xk_s[cur][m][ee];
                gy[jj] = (g_s[ee] * xh[jj] + bt_s[ee] - tgt) * g_s[ee];
                sgy += gy[jj]; sgx += gy[jj] * xh[jj];
            }
            sgy = red16_dpp(sgy); sgx = red16_dpp(sgx);
            const float sc = rstd * (1.f / 64.f);
#pragma unroll
            for (int jj = 0; jj < 4; ++jj)
                grad_s[m][e0 + jj] = (64.f * gy[jj] - sgy - xh[jj] * sgx) * sc;

            const int i3 = m, j3 = (tid & 15);
            float cf = 0.f;
            if (j3 <= i3) {
                float s = 0.f;
#pragma unroll
                for (int d = 0; d < 64; d += 4) {
                    float4 a  = *reinterpret_cast<float4*>(&xq_s[cur][i3][d]);
                    float4 bq = *reinterpret_cast<float4*>(&xk_s[cur][j3][d]);
                    s += a.x * bq.x + a.y * bq.y + a.z * bq.z + a.w * bq.w;
                }
                cf = tokv_s[i3] * lrs_s[cur][j3] * (1.f / 64.f) * (1.f + s);
            }
            coef_s[i3][j3] = cf;
            if (tid < 16) alpha_s[tid] = tokv_s[15] * lrs_s[cur][tid] * (1.f / 64.f);
        }
        __syncthreads();

        {
            const int m = tid >> 4, e0 = (tid & 15) * 4;
            float zf[4];
#pragma unroll
            for (int jj = 0; jj < 4; ++jj) zf[jj] = zb[jj] + b1_s[cur][e0 + jj];
            for (int j = 0; j <= m; ++j) {
                float cfv = coef_s[m][j];
                float4 g4 = *reinterpret_cast<float4*>(&grad_s[j][e0]);
                zf[0] = fmaf(-cfv, g4.x, zf[0]);
                zf[1] = fmaf(-cfv, g4.y, zf[1]);
                zf[2] = fmaf(-cfv, g4.z, zf[2]);
                zf[3] = fmaf(-cfv, g4.w, zf[3]);
            }
            float lsum = red16_dpp(zf[0] + zf[1] + zf[2] + zf[3]);
            const float mu = lsum * (1.f / 64.f);
            float lss = 0.f;
#pragma unroll
            for (int jj = 0; jj < 4; ++jj) { float d = zf[jj] - mu; lss += d * d; }
            lss = red16_dpp(lss);
            const float rstd = 1.f / sqrtf(lss * (1.f / 64.f) + EPSV);
            float ov[4];
#pragma unroll
            for (int jj = 0; jj < 4; ++jj) {
                int ee = e0 + jj;
                ov[jj] = xq_s[cur][m][ee] + ((zf[jj] - mu) * rstd * g_s[ee] + bt_s[ee]);
            }
            size_t yoff = (size_t)(b * Nn + c * 16 + m) * 768 + h * 64 + e0;
            *reinterpret_cast<float4*>(&ybuf[yoff]) =
                make_float4(ov[0], ov[1], ov[2], ov[3]);
        }
        {
#pragma unroll
            for (int m = 0; m < 16; ++m) {
                float f = alpha_s[m] * grad_s[m][e];
                float xkv[16];
                *reinterpret_cast<float4*>(&xkv[0])  = *reinterpret_cast<float4*>(&xk_s[cur][m][q16 + 0]);
                *reinterpret_cast<float4*>(&xkv[4])  = *reinterpret_cast<float4*>(&xk_s[cur][m][q16 + 4]);
                *reinterpret_cast<float4*>(&xkv[8])  = *reinterpret_cast<float4*>(&xk_s[cur][m][q16 + 8]);
                *reinterpret_cast<float4*>(&xkv[12]) = *reinterpret_cast<float4*>(&xk_s[cur][m][q16 + 12]);
#pragma unroll
                for (int r = 0; r < 16; ++r)
                    W1own[r] = fmaf(-f, xkv[r], W1own[r]);
            }
            if (q == 0) {
                float sb = 0.f;
#pragma unroll
                for (int m = 0; m < 16; ++m)
                    sb += alpha_s[m] * grad_s[m][e];
                b1_s[nxt][e] = b1_s[cur][e] - sb;
            }
        }
        __syncthreads();
        cur = nxt;
    }
}

// ---------------------------------------------------------------------------
// Kernel 4a: post layernorm + gelu gate -> u.  One block per token.
// ---------------------------------------------------------------------------
__global__ __launch_bounds__(256) void post_gate_kernel(
    const float* __restrict__ ybuf, const float* __restrict__ P,
    const float* __restrict__ ps, const float* __restrict__ pb,
    float* __restrict__ u)
{
    const int t = blockIdx.x;
    const int tid = threadIdx.x;
    __shared__ float red_a[4], red_b[4];
    float v[3];
    float lsum = 0.f;
#pragma unroll
    for (int i = 0; i < 3; ++i) {
        int c = tid + i * 256;
        v[i] = ybuf[(size_t)t * 768 + c];
        lsum += v[i];
    }
#pragma unroll
    for (int m = 1; m < 64; m <<= 1) lsum += __shfl_xor(lsum, m);
    if ((tid & 63) == 0) red_a[tid >> 6] = lsum;
    __syncthreads();
    const float mu = (red_a[0] + red_a[1] + red_a[2] + red_a[3]) * (1.f / 768.f);
    float lv = 0.f;
#pragma unroll
    for (int i = 0; i < 3; ++i) { float d = v[i] - mu; lv += d * d; }
#pragma unroll
    for (int m = 1; m < 64; m <<= 1) lv += __shfl_xor(lv, m);
    if ((tid & 63) == 0) red_b[tid >> 6] = lv;
    __syncthreads();
    const float var = (red_b[0] + red_b[1] + red_b[2] + red_b[3]) * (1.f / 768.f);
    const float rstd = 1.f / sqrtf(var + EPSV);
#pragma unroll
    for (int i = 0; i < 3; ++i) {
        int c = tid + i * 256;
        float g = P[(size_t)t * PLD + 1536 + c];
        float gl = 0.5f * g * (1.f + tanhf(0.7978845608028654f * (g + 0.044715f * g * g * g)));
        u[(size_t)t * 768 + c] = gl * ((v[i] - mu) * rstd * ps[c] + pb[c]);
    }
}

// ---------------------------------------------------------------------------
// Launcher — scratch comes from static device globals, NOT d_ws.
// ---------------------------------------------------------------------------
extern "C" void kernel_launch(void* const* d_in, const int* in_sizes, int n_in,
                              void* d_out, int out_size, void* d_ws, size_t ws_size,
                              hipStream_t stream)
{
    const float* hs   = (const float*)d_in[0];
    const int*   pid  = (const int*)  d_in[1];
    const float* wq   = (const float*)d_in[2];
    const float* wv   = (const float*)d_in[3];
    const float* wo   = (const float*)d_in[4];
    const float* wg   = (const float*)d_in[5];
    const float* cqk  = (const float*)d_in[6];
    const float* cqb  = (const float*)d_in[7];
    const float* ckk  = (const float*)d_in[8];
    const float* ckb  = (const float*)d_in[9];
    const float* lrw  = (const float*)d_in[10];
    const float* lrb  = (const float*)d_in[11];
    const float* lti  = (const float*)d_in[12];
    const float* gam  = (const float*)d_in[13];
    const float* bet  = (const float*)d_in[14];
    const float* ps   = (const float*)d_in[15];
    const float* pb   = (const float*)d_in[16];
    const float* W1g  = (const float*)d_in[17];
    const float* b1g  = (const float*)d_in[18];
    float* out = (float*)d_out;
    (void)d_ws; (void)ws_size; (void)in_sizes; (void)n_in; (void)out_size;

    float *tab = nullptr, *Wcat = nullptr, *P = nullptr, *XQp = nullptr,
          *XKp = nullptr, *XVp = nullptr, *lrv = nullptr, *ybuf = nullptr;
    hipGetSymbolAddress((void**)&tab,  HIP_SYMBOL(g_tab));
    hipGetSymbolAddress((void**)&Wcat, HIP_SYMBOL(g_Wcat));
    hipGetSymbolAddress((void**)&P,    HIP_SYMBOL(g_P));
    hipGetSymbolAddress((void**)&XQp,  HIP_SYMBOL(g_XQ));
    hipGetSymbolAddress((void**)&XKp,  HIP_SYMBOL(g_XK));
    hipGetSymbolAddress((void**)&XVp,  HIP_SYMBOL(g_XV));
    hipGetSymbolAddress((void**)&lrv,  HIP_SYMBOL(g_lrv));
    hipGetSymbolAddress((void**)&ybuf, HIP_SYMBOL(g_y));
    float* ubuf = XQp;   // XQp dead after scan

    hipLaunchKernelGGL(mfma_probe, dim3(1), dim3(64), 0, stream);
    hipLaunchKernelGGL(prep_kernel, dim3(2048), dim3(256), 0, stream,
                       wq, wv, wg, lrw, Wcat, tab);
    hipLaunchKernelGGL(gemm_bf16x3, dim3(19, 64), dim3(256), 0, stream,
                       hs, Hdim, Wcat, PLD, P, PLD, Bb * Nn, NCOLS, Hdim);
    hipLaunchKernelGGL(conv_rope_kernel, dim3(Bb * Nn), dim3(256), 0, stream,
                       P, pid, cqk, cqb, ckk, ckb, lrb, tab, XQp, XKp, XVp, lrv);
    hipLaunchKernelGGL(ttt_scan_kernel, dim3(NH, Bb), dim3(256), 0, stream,
                       XQp, XKp, XVp, lrv, W1g, b1g, gam, bet, lti, ybuf);
    hipLaunchKernelGGL(post_gate_kernel, dim3(Bb * Nn), dim3(256), 0, stream,
                       ybuf, P, ps, pb, ubuf);
    hipLaunchKernelGGL(gemm_bf16x3, dim3(6, 64), dim3(256), 0, stream,
                       ubuf, Hdim, wo, Hdim, out, Hdim, Bb * Nn, Hdim, Hdim);
}